// Round 6
// baseline (809.307 us; speedup 1.0000x reference)
//
#include <hip/hip_runtime.h>

// ConditionalCNF via MFMA (round 11): r10 structure + churn-proofed poly tanh.
// Model (fits r5/r6/r9/r10 with full static counts, +/-2%): TRANS=16cyc
// wave64, main=2cyc -> TRANS is 61% of VALU-busy.  r8's poly attempt was
// right but its float2v constants forced per-call v_mov materialization
// (~+650cyc/stage churn, visible in the fit).  This round re-lands it with:
//   - scalar Horner (v_fma_f32 legally reads 1 SGPR operand)
//   - coefficients pinned to SGPRs via readfirstlane ONCE at kernel entry
//   - r10's launch_bounds headroom retained (no pressure-remat)
//   u = exp2(-|xs|) in (0,1]   (neg+abs fold into v_exp src mods; no
//                               overflow path, saturation handled by P4(0))
//   tanh|x| = P4(u)            (max err ~5e-4 << 4e-3 bf16 pack error;
//                               HW-validated in r8: passed, absmax 0.0714)
//   tanh    = copysign(P4, xs) (v_bfi_b32 with SGPR mask)
// Per pair: 6 main + 3 TRANS (60cyc) -> 10 main + 2 TRANS (52cyc);
// x32 pairs/stage = -256 cyc of 2511 ~= -10%.
//
// Verified layouts (rounds 2+4+6 passed):
//   A-frag:  A[m=lane&15][k=(lane>>4)*8+j]
//   B-frag:  B[k=(lane>>4)*8+j][n=lane&15]
//   C/D:     col=lane&15, row=(lane>>4)*4+reg
//
// Scaling (s = 2*log2 e): W1z, c1, W2, b2 pre-scaled by s.  d-path carries
// s^2, compensated once per b via pd *= 1/s^2.

typedef __attribute__((ext_vector_type(8))) short short8;
typedef __attribute__((ext_vector_type(4))) float floatx4;
typedef __attribute__((ext_vector_type(2))) float float2v;

constexpr int NSTEPS = 20;
constexpr float SCL = 2.8853900817779268f;   // 2*log2(e)

struct U128 { unsigned a, b, c, d; };

__device__ __forceinline__ float fexp2(float x) {
#if __has_builtin(__builtin_amdgcn_exp2f)
    return __builtin_amdgcn_exp2f(x);
#else
    return exp2f(x);
#endif
}

__device__ __forceinline__ float2v vfma(float2v a, float2v b, float2v c) {
#if __has_builtin(__builtin_elementwise_fma)
    return __builtin_elementwise_fma(a, b, c);
#else
    float2v d; d.x = fmaf(a.x, b.x, c.x); d.y = fmaf(a.y, b.y, c.y); return d;
#endif
}

// force a float constant into an SGPR (one-time v_mov+readfirstlane at entry;
// thereafter a free VOP3 scalar operand -- no per-use materialization)
__device__ __forceinline__ float spin(float x) {
    return __builtin_bit_cast(float,
        __builtin_amdgcn_readfirstlane(__builtin_bit_cast(int, x)));
}

// two f32 -> bf16x2 in ONE instruction (RNE).  lo16=bf16(a), hi16=bf16(b).
__device__ __forceinline__ unsigned cvtpk_bf16(float a, float b) {
    unsigned r;
    asm("v_cvt_pk_bf16_f32 %0, %1, %2" : "=v"(r) : "v"(a), "v"(b));
    return r;
}

// pack two f32 -> bf16x2, round-half-up (+0x8000) -- setup only
__device__ __forceinline__ unsigned pack2bf(float a, float b) {
    unsigned ua = __builtin_bit_cast(unsigned, a) + 0x8000u;
    unsigned ub = __builtin_bit_cast(unsigned, b) + 0x8000u;
    return __builtin_amdgcn_perm(ub, ua, 0x07060302u);   // lo16=bf16(a), hi16=bf16(b)
}
// truncating pack (1 v_perm) — used on the d-path (no ODE feedback; bias ~2^-10)
__device__ __forceinline__ unsigned pack2bf_trunc(float2v v) {
    return __builtin_amdgcn_perm(__builtin_bit_cast(unsigned, v.y),
                                 __builtin_bit_cast(unsigned, v.x), 0x07060302u);
}
__device__ __forceinline__ float bf2f(unsigned bf) {
    return __builtin_bit_cast(float, bf << 16);
}

__device__ __forceinline__ float swz16(float x) {   // fetch value from lane^16
    return __builtin_bit_cast(float,
        __builtin_amdgcn_ds_swizzle(__builtin_bit_cast(int, x), 0x401F));
}
__device__ __forceinline__ float bperm(int addr, float x) {
    return __builtin_bit_cast(float,
        __builtin_amdgcn_ds_bpermute(addr, __builtin_bit_cast(int, x)));
}

// 4x4 transpose-reduce butterfly over quarter-groups.
// Input: p[b] = partial sum for sample 16*b + (lane&15), held by every lane.
// Output: lane l = 16*q + c receives the FULL sum for its own sample 16*q + c.
__device__ __forceinline__ float xreduce(float p0, float p1, float p2, float p3,
                                         bool q0, bool q1, int addrX) {
    const float keep1 = q0 ? p1 : p0;          // b with bit0(b)==bit0(q), pair {0,1}
    const float send1 = q0 ? p0 : p1;
    const float keep2 = q0 ? p3 : p2;          // pair {2,3}
    const float send2 = q0 ? p2 : p3;
    const float slo = keep1 + swz16(send1);    // sum over {q, q^1}
    const float shi = keep2 + swz16(send2);
    const float keep = q1 ? shi : slo;         // b with bit1(b)==bit1(q)
    const float send = q1 ? slo : shi;
    return keep + bperm(addrX, send);          // + sum over {q^2, q^3}
}

__global__ __launch_bounds__(256, 3) void cnf_mfma(
    const float* __restrict__ Tin, const float* __restrict__ cond,
    const float* __restrict__ W1, const float* __restrict__ b1,
    const float* __restrict__ W2, const float* __restrict__ b2,
    const float* __restrict__ W3, const float* __restrict__ b3,
    float* __restrict__ out, int B)
{
    const int tid   = threadIdx.x;
    const int lane  = tid & 63;
    const int wbase = blockIdx.x * 256 + (tid >> 6) * 64;

    const int c  = lane & 15;          // sample-within-16-block (D col); W2 row select
    const int qk = lane >> 4;          // quarter: k-chunk select; D row group
    const bool q0 = (qk & 1) != 0;
    const bool q1 = (qk & 2) != 0;

    // ---- tanh poly coefficients, pinned to SGPRs (zero in-loop movs) ----
    const float C4 = spin( 0.313706f);
    const float C3 = spin(-1.084553f);
    const float C2 = spin( 1.743936f);
    const float C1 = spin(-1.972222f);
    const float C0 = spin( 0.999493f);

    // tanh with pre-scaled input xs = 2*log2(e)*x.
    // u = exp2(-|xs|); tanh|x| = (1-u)/(1+u) ~ P4(u); sign via v_bfi.
    auto tanh1 = [&](float xs) -> float {
        const float u = fexp2(-__builtin_fabsf(xs));
        float p = fmaf(C4, u, C3);
        p = fmaf(p, u, C2);
        p = fmaf(p, u, C1);
        p = fmaf(p, u, C0);
        return __builtin_copysignf(p, xs);
    };
    auto tanh2 = [&](float2v xs) -> float2v {
        return float2v{tanh1(xs.x), tanh1(xs.y)};
    };

    int addrB[4];                      // z-broadcast source lane for block b
#pragma unroll
    for (int b = 0; b < 4; ++b) addrB[b] = (16 * b + c) * 4;
    const int addrX = (lane ^ 32) * 4; // xor32 partner for the butterfly

    const float is2 = 1.0f / (SCL * SCL);

    // ---- W2 fragments (A operand): A[m=c+16t][k=qk*8+j] = s*W2[c+16t][...],
    //      hi/lo bf16 split. ----
    short8 Whi[2], Wlo[2];
#pragma unroll
    for (int t = 0; t < 2; ++t) {
        const int u = c + 16 * t;
        const float* w2r = W2 + u * 32 + qk * 8;
        unsigned hu[4], lu[4];
#pragma unroll
        for (int p = 0; p < 4; ++p) {
            const float w0 = SCL * w2r[2 * p], w1v = SCL * w2r[2 * p + 1];
            const unsigned h0 = (__builtin_bit_cast(unsigned, w0) + 0x8000u) >> 16;
            const unsigned h1 = (__builtin_bit_cast(unsigned, w1v) + 0x8000u) >> 16;
            hu[p] = h0 | (h1 << 16);
            lu[p] = pack2bf(w0 - bf2f(h0), w1v - bf2f(h1));
        }
        Whi[t] = __builtin_bit_cast(short8, U128{hu[0], hu[1], hu[2], hu[3]});
        Wlo[t] = __builtin_bit_cast(short8, U128{lu[0], lu[1], lu[2], lu[3]});
    }

    // ---- per-lane D-ROW constants: rows u = 4*qk + r (+16t) ----
    const int r0 = 4 * qk;
    const floatx4 cinit0 = {SCL * b2[r0],      SCL * b2[r0 + 1],
                            SCL * b2[r0 + 2],  SCL * b2[r0 + 3]};
    const floatx4 cinit1 = {SCL * b2[16 + r0],     SCL * b2[16 + r0 + 1],
                            SCL * b2[16 + r0 + 2], SCL * b2[16 + r0 + 3]};
    const floatx4 zero = {0.0f, 0.0f, 0.0f, 0.0f};

    const float2v w3a_lo = {W3[r0],          W3[r0 + 1]};
    const float2v w3a_hi = {W3[r0 + 2],      W3[r0 + 3]};
    const float2v w3b_lo = {W3[16 + r0],     W3[16 + r0 + 1]};
    const float2v w3b_hi = {W3[16 + r0 + 2], W3[16 + r0 + 3]};

    // ---- layer-1 constants for this lane's k-chunk (pre-scaled by s) ----
    float2v w1z2[4];
#pragma unroll
    for (int p = 0; p < 4; ++p)
        w1z2[p] = float2v{SCL * W1[(qk * 8 + 2 * p) * 9],
                          SCL * W1[(qk * 8 + 2 * p + 1) * 9]};

    float2v c12[4][4];
#pragma unroll
    for (int b = 0; b < 4; ++b) {
        int s = wbase + 16 * b + c;
        if (s > B - 1) s = B - 1;
        const float4* c4 = reinterpret_cast<const float4*>(cond + (size_t)s * 8);
        const float4 ca = c4[0], cb = c4[1];
        const float cd[8] = {ca.x, ca.y, ca.z, ca.w, cb.x, cb.y, cb.z, cb.w};
        float c1[8];
#pragma unroll
        for (int j = 0; j < 8; ++j) {
            const int k = qk * 8 + j;
            float acc = b1[k];
#pragma unroll
            for (int jj = 0; jj < 8; ++jj) acc = fmaf(cd[jj], W1[k * 9 + 1 + jj], acc);
            c1[j] = SCL * acc;
        }
#pragma unroll
        for (int p = 0; p < 4; ++p) c12[b][p] = float2v{c1[2 * p], c1[2 * p + 1]};
    }

    const float b3v = b3[0];
    const int sg = wbase + lane;           // identity ownership
    float z = Tin[sg < B ? sg : B - 1];
    float dlog = 0.0f;
    const float dt = 1.0f / (float)NSTEPS;
    const float2v one = {1.0f, 1.0f};

    for (int step = 0; step < NSTEPS; ++step) {
        float kz = 0.0f, accz = 0.0f, accl = 0.0f;
#pragma unroll 1
        for (int s4 = 0; s4 < 4; ++s4) {
            const float a = (s4 == 0) ? 0.0f : ((s4 == 3) ? dt : 0.5f * dt);
            const float w = ((s4 == 0) | (s4 == 3)) ? (dt * (1.0f / 6.0f))
                                                    : (dt * (1.0f / 3.0f));
            const int zi = __builtin_bit_cast(int, fmaf(a, kz, z));
            float ph[4], pd[4];

#pragma unroll
            for (int b = 0; b < 4; ++b) {
                const float zin = __builtin_bit_cast(
                    float, __builtin_amdgcn_ds_bpermute(addrB[b], zi));
                const float2v zz = {zin, zin};

                // ---- B-frag prep: h1 (bf16, RNE cvt_pk) and s*d1 (bf16, trunc) ----
                unsigned ahp[4], adp[4];
#pragma unroll
                for (int p = 0; p < 4; ++p) {
                    const float2v xs = vfma(zz, w1z2[p], c12[b][p]);  // s*preact1
                    const float2v h  = tanh2(xs);
                    ahp[p] = cvtpk_bf16(h.x, h.y);
                    const float2v hh = h * h;
                    adp[p] = pack2bf_trunc(vfma(hh, -w1z2[p], w1z2[p])); // (1-h^2)*s*w1z
                }
                const short8 Ah = __builtin_bit_cast(short8, U128{ahp[0], ahp[1], ahp[2], ahp[3]});
                const short8 Ad = __builtin_bit_cast(short8, U128{adp[0], adp[1], adp[2], adp[3]});

                // ---- transposed layer-2: D[u][sample] = (s*W2) @ h1^T ----
                floatx4 Dh0 = __builtin_amdgcn_mfma_f32_16x16x32_bf16(Wlo[0], Ah, cinit0, 0, 0, 0);
                Dh0         = __builtin_amdgcn_mfma_f32_16x16x32_bf16(Whi[0], Ah, Dh0,    0, 0, 0);
                floatx4 Dh1 = __builtin_amdgcn_mfma_f32_16x16x32_bf16(Wlo[1], Ah, cinit1, 0, 0, 0);
                Dh1         = __builtin_amdgcn_mfma_f32_16x16x32_bf16(Whi[1], Ah, Dh1,    0, 0, 0);
                floatx4 Dd0 = __builtin_amdgcn_mfma_f32_16x16x32_bf16(Wlo[0], Ad, zero,   0, 0, 0);
                Dd0         = __builtin_amdgcn_mfma_f32_16x16x32_bf16(Whi[0], Ad, Dd0,    0, 0, 0);
                floatx4 Dd1 = __builtin_amdgcn_mfma_f32_16x16x32_bf16(Wlo[1], Ad, zero,   0, 0, 0);
                Dd1         = __builtin_amdgcn_mfma_f32_16x16x32_bf16(Whi[1], Ad, Dd1,    0, 0, 0);

                // ---- lane-local W3 contraction over the 8 hidden rows ----
                const float2v Dh0lo = __builtin_shufflevector(Dh0, Dh0, 0, 1);
                const float2v Dh0hi = __builtin_shufflevector(Dh0, Dh0, 2, 3);
                const float2v Dh1lo = __builtin_shufflevector(Dh1, Dh1, 0, 1);
                const float2v Dh1hi = __builtin_shufflevector(Dh1, Dh1, 2, 3);
                const float2v Dd0lo = __builtin_shufflevector(Dd0, Dd0, 0, 1);
                const float2v Dd0hi = __builtin_shufflevector(Dd0, Dd0, 2, 3);
                const float2v Dd1lo = __builtin_shufflevector(Dd1, Dd1, 0, 1);
                const float2v Dd1hi = __builtin_shufflevector(Dd1, Dd1, 2, 3);

                const float2v h2a_lo = tanh2(Dh0lo);
                const float2v h2a_hi = tanh2(Dh0hi);
                const float2v h2b_lo = tanh2(Dh1lo);
                const float2v h2b_hi = tanh2(Dh1hi);

                float2v az = h2a_lo * w3a_lo;
                az = vfma(h2a_hi, w3a_hi, az);
                az = vfma(h2b_lo, w3b_lo, az);
                az = vfma(h2b_hi, w3b_hi, az);
                ph[b] = az.x + az.y;

                const float2v ua_lo = vfma(h2a_lo, -h2a_lo, one);
                const float2v ua_hi = vfma(h2a_hi, -h2a_hi, one);
                const float2v ub_lo = vfma(h2b_lo, -h2b_lo, one);
                const float2v ub_hi = vfma(h2b_hi, -h2b_hi, one);

                float2v dv = (Dd0lo * w3a_lo) * ua_lo;
                dv = vfma(Dd0hi * w3a_hi, ua_hi, dv);
                dv = vfma(Dd1lo * w3b_lo, ub_lo, dv);
                dv = vfma(Dd1hi * w3b_hi, ub_hi, dv);
                pd[b] = (dv.x + dv.y) * is2;       // s^-2 folded once per block
            }

            // ---- deferred 4x4 butterfly transpose-reduce (once per stage) ----
            kz = xreduce(ph[0], ph[1], ph[2], ph[3], q0, q1, addrX) + b3v;
            accz = fmaf(w, kz, accz);
            accl = fmaf(w, xreduce(pd[0], pd[1], pd[2], pd[3], q0, q1, addrX), accl);
        }
        z += accz;
        dlog += accl;
    }

    if (sg < B) {
        out[sg] = z;
        out[(size_t)B + sg] = dlog;
    }
}

extern "C" void kernel_launch(void* const* d_in, const int* in_sizes, int n_in,
                              void* d_out, int out_size, void* d_ws, size_t ws_size,
                              hipStream_t stream) {
    const float* T    = (const float*)d_in[0];
    const float* cond = (const float*)d_in[1];
    const float* W1   = (const float*)d_in[2];
    const float* b1   = (const float*)d_in[3];
    const float* W2   = (const float*)d_in[4];
    const float* b2   = (const float*)d_in[5];
    const float* W3   = (const float*)d_in[6];
    const float* b3   = (const float*)d_in[7];
    float* out = (float*)d_out;

    const int B = in_sizes[0];
    const int grid = (B + 255) / 256;
    cnf_mfma<<<grid, 256, 0, stream>>>(T, cond, W1, b1, W2, b2, W3, b3, out, B);
}

// Round 7
// 734.255 us; speedup vs baseline: 1.1022x; 1.1022x over previous
//
#include <hip/hip_runtime.h>

// ConditionalCNF via MFMA (round 12): r10 base (837us verified) + two
// non-tanh deletions.  Model (closed by r10/r11 pair): TRANS=8cyc wave64,
// main=2cyc, VALUBusy INCLUDES MfmaUtil cycles; tanh is at its exp-based
// floor (rcp<->poly is an exact wash) -- TRANS axis closed.  This round:
//  1. dlog reduction DEFERRED out of the time loop: xreduce is linear with
//     time-invariant routing, so accumulate P[b] += w*pd[b] (4 fma/stage)
//     and do ONE xreduce(+is2) in the epilogue instead of 80.  Removes
//     10 main + 3 DS + a ~100cyc serial DS chain per stage.  Only kz's
//     xreduce remains (true ODE feedback).
//  2. d-path MFMA single-precision: Dd = Whi@Ad only (drop Wlo): the d-path
//     already carries ~0.4% from Ad trunc-pack; bf16 W2 adds ~0.2% there
//     while deleting 8 of 32 MFMAs/stage.  h-path keeps the full hi/lo
//     split (feeds the z feedback).
//
// Verified layouts (rounds 2+4+6 passed):
//   A-frag:  A[m=lane&15][k=(lane>>4)*8+j]
//   B-frag:  B[k=(lane>>4)*8+j][n=lane&15]
//   C/D:     col=lane&15, row=(lane>>4)*4+reg
//
// Scaling (s = 2*log2 e): W1z, c1, W2, b2 pre-scaled by s.  d-path carries
// s^2, compensated ONCE at the end via dlog *= 1/s^2.

typedef __attribute__((ext_vector_type(8))) short short8;
typedef __attribute__((ext_vector_type(4))) float floatx4;
typedef __attribute__((ext_vector_type(2))) float float2v;

constexpr int NSTEPS = 20;
constexpr float SCL = 2.8853900817779268f;   // 2*log2(e)

struct U128 { unsigned a, b, c, d; };

__device__ __forceinline__ float fexp2(float x) {
#if __has_builtin(__builtin_amdgcn_exp2f)
    return __builtin_amdgcn_exp2f(x);
#else
    return exp2f(x);
#endif
}

__device__ __forceinline__ float2v vfma(float2v a, float2v b, float2v c) {
#if __has_builtin(__builtin_elementwise_fma)
    return __builtin_elementwise_fma(a, b, c);
#else
    float2v d; d.x = fmaf(a.x, b.x, c.x); d.y = fmaf(a.y, b.y, c.y); return d;
#endif
}

// packed tanh, pre-scaled inputs xs = 2*log2(e)*x.
// tanh(x) = 1 - 2/(exp2(xs)+1).  ONE rcp per pair, 6 main ops, inline consts:
//   rr = rcp(dx*dy); q = -2*rr; tanh.x = fma(q,dy,1); tanh.y = fma(q,dx,1).
// Overflow: dx*dy < 3.4e38 holds for |preact| sum < 44 (data-bounded ~12).
__device__ __forceinline__ float2v tanh_pk(float2v xs) {
    const float ex = fexp2(xs.x);
    const float ey = fexp2(xs.y);
    const float dx = ex + 1.0f;
    const float dy = ey + 1.0f;
    const float rr = __builtin_amdgcn_rcpf(dx * dy);
    const float q  = rr * -2.0f;
    return float2v{fmaf(q, dy, 1.0f), fmaf(q, dx, 1.0f)};
}

// two f32 -> bf16x2 in ONE instruction (RNE).  lo16=bf16(a), hi16=bf16(b).
__device__ __forceinline__ unsigned cvtpk_bf16(float a, float b) {
    unsigned r;
    asm("v_cvt_pk_bf16_f32 %0, %1, %2" : "=v"(r) : "v"(a), "v"(b));
    return r;
}

// pack two f32 -> bf16x2, round-half-up (+0x8000) -- setup only
__device__ __forceinline__ unsigned pack2bf(float a, float b) {
    unsigned ua = __builtin_bit_cast(unsigned, a) + 0x8000u;
    unsigned ub = __builtin_bit_cast(unsigned, b) + 0x8000u;
    return __builtin_amdgcn_perm(ub, ua, 0x07060302u);   // lo16=bf16(a), hi16=bf16(b)
}
// truncating pack (1 v_perm) — used on the d-path (no ODE feedback; bias ~2^-10)
__device__ __forceinline__ unsigned pack2bf_trunc(float2v v) {
    return __builtin_amdgcn_perm(__builtin_bit_cast(unsigned, v.y),
                                 __builtin_bit_cast(unsigned, v.x), 0x07060302u);
}
__device__ __forceinline__ float bf2f(unsigned bf) {
    return __builtin_bit_cast(float, bf << 16);
}

__device__ __forceinline__ float swz16(float x) {   // fetch value from lane^16
    return __builtin_bit_cast(float,
        __builtin_amdgcn_ds_swizzle(__builtin_bit_cast(int, x), 0x401F));
}
__device__ __forceinline__ float bperm(int addr, float x) {
    return __builtin_bit_cast(float,
        __builtin_amdgcn_ds_bpermute(addr, __builtin_bit_cast(int, x)));
}

// 4x4 transpose-reduce butterfly over quarter-groups.
// Input: p[b] = partial sum for sample 16*b + (lane&15), held by every lane.
// Output: lane l = 16*q + c receives the FULL sum for its own sample 16*q + c.
__device__ __forceinline__ float xreduce(float p0, float p1, float p2, float p3,
                                         bool q0, bool q1, int addrX) {
    const float keep1 = q0 ? p1 : p0;          // b with bit0(b)==bit0(q), pair {0,1}
    const float send1 = q0 ? p0 : p1;
    const float keep2 = q0 ? p3 : p2;          // pair {2,3}
    const float send2 = q0 ? p2 : p3;
    const float slo = keep1 + swz16(send1);    // sum over {q, q^1}
    const float shi = keep2 + swz16(send2);
    const float keep = q1 ? shi : slo;         // b with bit1(b)==bit1(q)
    const float send = q1 ? slo : shi;
    return keep + bperm(addrX, send);          // + sum over {q^2, q^3}
}

__global__ __launch_bounds__(256, 3) void cnf_mfma(
    const float* __restrict__ Tin, const float* __restrict__ cond,
    const float* __restrict__ W1, const float* __restrict__ b1,
    const float* __restrict__ W2, const float* __restrict__ b2,
    const float* __restrict__ W3, const float* __restrict__ b3,
    float* __restrict__ out, int B)
{
    const int tid   = threadIdx.x;
    const int lane  = tid & 63;
    const int wbase = blockIdx.x * 256 + (tid >> 6) * 64;

    const int c  = lane & 15;          // sample-within-16-block (D col); W2 row select
    const int qk = lane >> 4;          // quarter: k-chunk select; D row group
    const bool q0 = (qk & 1) != 0;
    const bool q1 = (qk & 2) != 0;

    int addrB[4];                      // z-broadcast source lane for block b
#pragma unroll
    for (int b = 0; b < 4; ++b) addrB[b] = (16 * b + c) * 4;
    const int addrX = (lane ^ 32) * 4; // xor32 partner for the butterfly

    const float is2 = 1.0f / (SCL * SCL);

    // ---- W2 fragments (A operand): A[m=c+16t][k=qk*8+j] = s*W2[c+16t][...],
    //      hi/lo bf16 split. ----
    short8 Whi[2], Wlo[2];
#pragma unroll
    for (int t = 0; t < 2; ++t) {
        const int u = c + 16 * t;
        const float* w2r = W2 + u * 32 + qk * 8;
        unsigned hu[4], lu[4];
#pragma unroll
        for (int p = 0; p < 4; ++p) {
            const float w0 = SCL * w2r[2 * p], w1v = SCL * w2r[2 * p + 1];
            const unsigned h0 = (__builtin_bit_cast(unsigned, w0) + 0x8000u) >> 16;
            const unsigned h1 = (__builtin_bit_cast(unsigned, w1v) + 0x8000u) >> 16;
            hu[p] = h0 | (h1 << 16);
            lu[p] = pack2bf(w0 - bf2f(h0), w1v - bf2f(h1));
        }
        Whi[t] = __builtin_bit_cast(short8, U128{hu[0], hu[1], hu[2], hu[3]});
        Wlo[t] = __builtin_bit_cast(short8, U128{lu[0], lu[1], lu[2], lu[3]});
    }

    // ---- per-lane D-ROW constants: rows u = 4*qk + r (+16t) ----
    const int r0 = 4 * qk;
    const floatx4 cinit0 = {SCL * b2[r0],      SCL * b2[r0 + 1],
                            SCL * b2[r0 + 2],  SCL * b2[r0 + 3]};
    const floatx4 cinit1 = {SCL * b2[16 + r0],     SCL * b2[16 + r0 + 1],
                            SCL * b2[16 + r0 + 2], SCL * b2[16 + r0 + 3]};
    const floatx4 zero = {0.0f, 0.0f, 0.0f, 0.0f};

    const float2v w3a_lo = {W3[r0],          W3[r0 + 1]};
    const float2v w3a_hi = {W3[r0 + 2],      W3[r0 + 3]};
    const float2v w3b_lo = {W3[16 + r0],     W3[16 + r0 + 1]};
    const float2v w3b_hi = {W3[16 + r0 + 2], W3[16 + r0 + 3]};

    // ---- layer-1 constants for this lane's k-chunk (pre-scaled by s) ----
    float2v w1z2[4];
#pragma unroll
    for (int p = 0; p < 4; ++p)
        w1z2[p] = float2v{SCL * W1[(qk * 8 + 2 * p) * 9],
                          SCL * W1[(qk * 8 + 2 * p + 1) * 9]};

    float2v c12[4][4];
#pragma unroll
    for (int b = 0; b < 4; ++b) {
        int s = wbase + 16 * b + c;
        if (s > B - 1) s = B - 1;
        const float4* c4 = reinterpret_cast<const float4*>(cond + (size_t)s * 8);
        const float4 ca = c4[0], cb = c4[1];
        const float cd[8] = {ca.x, ca.y, ca.z, ca.w, cb.x, cb.y, cb.z, cb.w};
        float c1[8];
#pragma unroll
        for (int j = 0; j < 8; ++j) {
            const int k = qk * 8 + j;
            float acc = b1[k];
#pragma unroll
            for (int jj = 0; jj < 8; ++jj) acc = fmaf(cd[jj], W1[k * 9 + 1 + jj], acc);
            c1[j] = SCL * acc;
        }
#pragma unroll
        for (int p = 0; p < 4; ++p) c12[b][p] = float2v{c1[2 * p], c1[2 * p + 1]};
    }

    const float b3v = b3[0];
    const int sg = wbase + lane;           // identity ownership
    float z = Tin[sg < B ? sg : B - 1];
    const float dt = 1.0f / (float)NSTEPS;
    const float2v one = {1.0f, 1.0f};

    // deferred dlog partials, one per b-slot (reduced ONCE in the epilogue)
    float P0 = 0.0f, P1 = 0.0f, P2 = 0.0f, P3 = 0.0f;

    for (int step = 0; step < NSTEPS; ++step) {
        float kz = 0.0f, accz = 0.0f;
#pragma unroll 1
        for (int s4 = 0; s4 < 4; ++s4) {
            const float a = (s4 == 0) ? 0.0f : ((s4 == 3) ? dt : 0.5f * dt);
            const float w = ((s4 == 0) | (s4 == 3)) ? (dt * (1.0f / 6.0f))
                                                    : (dt * (1.0f / 3.0f));
            const int zi = __builtin_bit_cast(int, fmaf(a, kz, z));
            float ph[4];

#pragma unroll
            for (int b = 0; b < 4; ++b) {
                const float zin = __builtin_bit_cast(
                    float, __builtin_amdgcn_ds_bpermute(addrB[b], zi));
                const float2v zz = {zin, zin};

                // ---- B-frag prep: h1 (bf16, RNE cvt_pk) and s*d1 (bf16, trunc) ----
                unsigned ahp[4], adp[4];
#pragma unroll
                for (int p = 0; p < 4; ++p) {
                    const float2v xs = vfma(zz, w1z2[p], c12[b][p]);  // s*preact1
                    const float2v h  = tanh_pk(xs);
                    ahp[p] = cvtpk_bf16(h.x, h.y);
                    const float2v hh = h * h;
                    adp[p] = pack2bf_trunc(vfma(hh, -w1z2[p], w1z2[p])); // (1-h^2)*s*w1z
                }
                const short8 Ah = __builtin_bit_cast(short8, U128{ahp[0], ahp[1], ahp[2], ahp[3]});
                const short8 Ad = __builtin_bit_cast(short8, U128{adp[0], adp[1], adp[2], adp[3]});

                // ---- transposed layer-2: D[u][sample] = (s*W2) @ h1^T ----
                floatx4 Dh0 = __builtin_amdgcn_mfma_f32_16x16x32_bf16(Wlo[0], Ah, cinit0, 0, 0, 0);
                Dh0         = __builtin_amdgcn_mfma_f32_16x16x32_bf16(Whi[0], Ah, Dh0,    0, 0, 0);
                floatx4 Dh1 = __builtin_amdgcn_mfma_f32_16x16x32_bf16(Wlo[1], Ah, cinit1, 0, 0, 0);
                Dh1         = __builtin_amdgcn_mfma_f32_16x16x32_bf16(Whi[1], Ah, Dh1,    0, 0, 0);
                // d-path: single-precision W2 (Whi only) -- Ad is already
                // trunc-packed; Wlo's 2^-9 contribution is below that noise.
                const floatx4 Dd0 = __builtin_amdgcn_mfma_f32_16x16x32_bf16(Whi[0], Ad, zero, 0, 0, 0);
                const floatx4 Dd1 = __builtin_amdgcn_mfma_f32_16x16x32_bf16(Whi[1], Ad, zero, 0, 0, 0);

                // ---- lane-local W3 contraction over the 8 hidden rows ----
                const float2v Dh0lo = __builtin_shufflevector(Dh0, Dh0, 0, 1);
                const float2v Dh0hi = __builtin_shufflevector(Dh0, Dh0, 2, 3);
                const float2v Dh1lo = __builtin_shufflevector(Dh1, Dh1, 0, 1);
                const float2v Dh1hi = __builtin_shufflevector(Dh1, Dh1, 2, 3);
                const float2v Dd0lo = __builtin_shufflevector(Dd0, Dd0, 0, 1);
                const float2v Dd0hi = __builtin_shufflevector(Dd0, Dd0, 2, 3);
                const float2v Dd1lo = __builtin_shufflevector(Dd1, Dd1, 0, 1);
                const float2v Dd1hi = __builtin_shufflevector(Dd1, Dd1, 2, 3);

                const float2v h2a_lo = tanh_pk(Dh0lo);
                const float2v h2a_hi = tanh_pk(Dh0hi);
                const float2v h2b_lo = tanh_pk(Dh1lo);
                const float2v h2b_hi = tanh_pk(Dh1hi);

                float2v az = h2a_lo * w3a_lo;
                az = vfma(h2a_hi, w3a_hi, az);
                az = vfma(h2b_lo, w3b_lo, az);
                az = vfma(h2b_hi, w3b_hi, az);
                ph[b] = az.x + az.y;

                const float2v ua_lo = vfma(h2a_lo, -h2a_lo, one);
                const float2v ua_hi = vfma(h2a_hi, -h2a_hi, one);
                const float2v ub_lo = vfma(h2b_lo, -h2b_lo, one);
                const float2v ub_hi = vfma(h2b_hi, -h2b_hi, one);

                float2v dv = (Dd0lo * w3a_lo) * ua_lo;
                dv = vfma(Dd0hi * w3a_hi, ua_hi, dv);
                dv = vfma(Dd1lo * w3b_lo, ub_lo, dv);
                dv = vfma(Dd1hi * w3b_hi, ub_hi, dv);
                const float pdb = dv.x + dv.y;
                // deferred: accumulate w*pd into the b-slot partial
                if (b == 0) P0 = fmaf(w, pdb, P0);
                else if (b == 1) P1 = fmaf(w, pdb, P1);
                else if (b == 2) P2 = fmaf(w, pdb, P2);
                else P3 = fmaf(w, pdb, P3);
            }

            // ---- h-path butterfly transpose-reduce (feedback, must stay) ----
            kz = xreduce(ph[0], ph[1], ph[2], ph[3], q0, q1, addrX) + b3v;
            accz = fmaf(w, kz, accz);
        }
        z += accz;
    }

    // ---- epilogue: ONE deferred reduction for dlog (linear, time-invariant
    //      routing), s^-2 compensation folded in once ----
    const float dlog = xreduce(P0, P1, P2, P3, q0, q1, addrX) * is2;

    if (sg < B) {
        out[sg] = z;
        out[(size_t)B + sg] = dlog;
    }
}

extern "C" void kernel_launch(void* const* d_in, const int* in_sizes, int n_in,
                              void* d_out, int out_size, void* d_ws, size_t ws_size,
                              hipStream_t stream) {
    const float* T    = (const float*)d_in[0];
    const float* cond = (const float*)d_in[1];
    const float* W1   = (const float*)d_in[2];
    const float* b1   = (const float*)d_in[3];
    const float* W2   = (const float*)d_in[4];
    const float* b2   = (const float*)d_in[5];
    const float* W3   = (const float*)d_in[6];
    const float* b3   = (const float*)d_in[7];
    float* out = (float*)d_out;

    const int B = in_sizes[0];
    const int grid = (B + 255) / 256;
    cnf_mfma<<<grid, 256, 0, stream>>>(T, cond, W1, b1, W2, b2, W3, b3, out, B);
}